// Round 14
// baseline (213.277 us; speedup 1.0000x reference)
//
#include <hip/hip_runtime.h>

#define KCODES 1024
#define CDIM   256
#define SP     16384           // D*H*W
#define ZQTOT  16777216        // B*C*D*H*W
#define NQ     65536           // B*D*H*W
#define BSTRIDE 4194304        // C*SP
#define MAX_AMB 12288
#define LOSS_SCALE 33554432.0  // 2^25 fixed-point deterministic loss
#define KEYMASK 0xFFFFFC00u
#define AMB_THR 6.0e-4f
#define BIAS    0.25f

#define QT2    128             // queries per block (main kernel)
#define NTILE  32              // 32 code-tiles of 32 codes
#define ROWB   528             // padded LDS bytes per code row (33*16)
#define TILEB  16896           // 32*528

using f32x4  = __attribute__((ext_vector_type(4)))  float;
using f32x16 = __attribute__((ext_vector_type(16))) float;
using bf16x8 = __attribute__((ext_vector_type(8)))  short;

__device__ __forceinline__ unsigned short f2bf(float x) {   // RNE f32->bf16
    unsigned u = __float_as_uint(x);
    u += 0x7fffu + ((u >> 16) & 1u);
    return (unsigned short)(u >> 16);
}
__device__ __forceinline__ unsigned umn(unsigned a, unsigned b){ return a < b ? a : b; }
__device__ __forceinline__ unsigned umx(unsigned a, unsigned b){ return a > b ? a : b; }

// ---- numpy pairwise_sum replication (base case n=128, 8 accumulators) ----
__device__ __forceinline__ float pw128_sq(const float* a) {
    float r[8];
    #pragma unroll
    for (int j = 0; j < 8; ++j) r[j] = __fmul_rn(a[j], a[j]);
    for (int i = 8; i < 128; i += 8) {
        #pragma unroll
        for (int j = 0; j < 8; ++j) r[j] = __fadd_rn(r[j], __fmul_rn(a[i+j], a[i+j]));
    }
    return __fadd_rn(__fadd_rn(__fadd_rn(r[0], r[1]), __fadd_rn(r[2], r[3])),
                     __fadd_rn(__fadd_rn(r[4], r[5]), __fadd_rn(r[6], r[7])));
}
__device__ __forceinline__ float pairwise256_sq(const float* a) {
    return __fadd_rn(pw128_sq(a), pw128_sq(a + 128));
}
// np.einsum SSE path: 4 mod-4 accumulators, separate mul/add roundings
__device__ __forceinline__ float np_dot256(const float* zr, const float* er) {
    float a0 = 0.f, a1 = 0.f, a2 = 0.f, a3 = 0.f;
    for (int i8 = 0; i8 < 256; i8 += 8) {
        a0 = __fadd_rn(a0, __fmul_rn(zr[i8+0], er[i8+0]));
        a1 = __fadd_rn(a1, __fmul_rn(zr[i8+1], er[i8+1]));
        a2 = __fadd_rn(a2, __fmul_rn(zr[i8+2], er[i8+2]));
        a3 = __fadd_rn(a3, __fmul_rn(zr[i8+3], er[i8+3]));
        a0 = __fadd_rn(a0, __fmul_rn(zr[i8+4], er[i8+4]));
        a1 = __fadd_rn(a1, __fmul_rn(zr[i8+5], er[i8+5]));
        a2 = __fadd_rn(a2, __fmul_rn(zr[i8+6], er[i8+6]));
        a3 = __fadd_rn(a3, __fmul_rn(zr[i8+7], er[i8+7]));
    }
    return __fadd_rn(__fadd_rn(a0, a1), __fadd_rn(a2, a3));
}

// ---------------- pre-pass: emb -> bf16 (hi only) + BIASED esq ----------------
__global__ __launch_bounds__(64)
void vq_prep(const float* __restrict__ emb, unsigned short* __restrict__ embh,
             float* __restrict__ esq_g) {
    const int k = blockIdx.x;
    const int l = threadIdx.x;
    float4 v = ((const float4*)(emb + (size_t)k * CDIM))[l];
    float s = v.x*v.x + v.y*v.y + v.z*v.z + v.w*v.w;
    unsigned short h0=f2bf(v.x), h1=f2bf(v.y), h2=f2bf(v.z), h3=f2bf(v.w);
    uint2 hh; hh.x = (unsigned)h0 | ((unsigned)h1<<16); hh.y = (unsigned)h2 | ((unsigned)h3<<16);
    *(uint2*)&embh[(size_t)k*CDIM + l*4] = hh;
    #pragma unroll
    for (int off = 32; off > 0; off >>= 1) s += __shfl_down(s, off, 64);
    if (l == 0) esq_g[k] = s + BIAS;   // biased: all scores positive -> raw-bit keys
}

// ------- MFMA main: r13 + LDS triple-buffer (2-deep pipeline, register-neutral) -------
__global__ __launch_bounds__(256, 2)
void vq_main_mfma(const float* __restrict__ z, const float* __restrict__ emb,
                  const unsigned short* __restrict__ embh,
                  const float* __restrict__ esq_g,
                  float* __restrict__ out, unsigned long long* __restrict__ loss_acc,
                  unsigned int* __restrict__ amb_cnt, uint4* __restrict__ wl4) {
    __shared__ __align__(16) unsigned char smem[3*TILEB + 4096];
    unsigned* top1 = (unsigned*)(smem + 3*TILEB);          // 128 u32
    unsigned* top2 = top1 + 128;
    unsigned* top3 = top2 + 128;
    float*    zsql = (float*)(top3 + 128);                 // 128 f32
    int*      fidx = (int*)(zsql + 128);                   // 128 i32
    float*    lpart = (float*)(fidx + 128);                // 2 f32

    const int t    = threadIdx.x;
    const int l    = t & 63;
    const int w    = t >> 6;
    const int half = l >> 5;
    const int lr   = l & 31;
    // XCD-bijective swizzle (nwg=512, 512%8==0)
    const int bid  = blockIdx.x;
    const int obid = ((bid & 7) << 6) + (bid >> 3);
    const int n0   = obid * QT2;
    const int b    = n0 >> 14;
    const int sp0  = n0 & 16383;
    const int wq0  = w * 32;
    const float* zb = z + (size_t)b * BSTRIDE + sp0 + wq0 + lr;
    const char* ebase = (const char*)embh;

    unsigned char* buf0 = smem;
    unsigned char* buf1 = smem + TILEB;
    unsigned char* buf2 = smem + 2*TILEB;

    #define STAGE_LOAD(st, tile)                                                     \
        { _Pragma("unroll")                                                          \
          for (int k_ = 0; k_ < 4; ++k_)                                             \
              st[k_] = *(const uint4*)(ebase + (size_t)(tile)*16384 +                \
                                       (size_t)(t + k_*256) * 16); }
    #define STAGE_WRITE(bufbase, st)                                                 \
        { _Pragma("unroll")                                                          \
          for (int k_ = 0; k_ < 4; ++k_) {                                           \
              const int idx_ = t + k_*256;                                           \
              *(uint4*)((bufbase) + (idx_ >> 5)*ROWB + (idx_ & 31)*16) = st[k_];     \
          } }

    uint4 st[4];
    STAGE_LOAD(st, 0);                 // tile 0

    // ---- A fragments in registers (covers tile-0 load latency) ----
    bf16x8 A[16];
    float zsq_p = 0.f;
    #pragma unroll
    for (int ks = 0; ks < 16; ++ks) {
        const float* zp = zb + (size_t)(ks*16 + half*8) * SP;
        float v[8];
        #pragma unroll
        for (int j = 0; j < 8; ++j) v[j] = zp[(size_t)j * SP];
        bf16x8 a;
        #pragma unroll
        for (int j = 0; j < 8; ++j) {
            zsq_p += v[j] * v[j];
            a[j] = (short)f2bf(v[j]);
        }
        A[ks] = a;
    }
    zsq_p += __shfl_xor(zsq_p, 32, 64);
    if (half == 0) zsql[wq0 + lr] = zsq_p;

    STAGE_WRITE(buf0, st);             // tile 0 -> buf0
    STAGE_LOAD(st, 1);                 // st = tile 1 (a full phase of cover)
    __syncthreads();

    unsigned m1v[16], m2v[16], m3v[16];
    #pragma unroll
    for (int s = 0; s < 16; ++s) { m1v[s]=0xFFFFFFFFu; m2v[s]=0xFFFFFFFFu; m3v[s]=0xFFFFFFFFu; }

    #define COMPUTE(bufbase, tile_)                                                  \
    {                                                                                \
        const float es = esq_g[(tile_)*32 + lr];                                     \
        const unsigned char* bb = (bufbase) + lr*ROWB + half*16;                     \
        f32x16 acc[4];                                                               \
        _Pragma("unroll")                                                            \
        for (int c_ = 0; c_ < 4; ++c_)                                               \
            acc[c_] = f32x16{0.f,0.f,0.f,0.f,0.f,0.f,0.f,0.f,                        \
                             0.f,0.f,0.f,0.f,0.f,0.f,0.f,0.f};                       \
        __builtin_amdgcn_s_setprio(1);                                               \
        _Pragma("unroll")                                                            \
        for (int ks = 0; ks < 16; ++ks) {                                            \
            const bf16x8 Bv = *(const bf16x8*)(bb + ks*32);                          \
            acc[ks & 3] = __builtin_amdgcn_mfma_f32_32x32x16_bf16(A[ks], Bv,         \
                                                                  acc[ks & 3], 0,0,0);\
        }                                                                            \
        __builtin_amdgcn_s_setprio(0);                                               \
        const unsigned kc = (unsigned)((tile_)*32 + lr);                             \
        _Pragma("unroll")                                                            \
        for (int s_ = 0; s_ < 16; ++s_) {                                            \
            const float dot = (acc[0][s_] + acc[1][s_]) + (acc[2][s_] + acc[3][s_]); \
            const float sc = __builtin_fmaf(-2.0f, dot, es);                         \
            const unsigned p = (__float_as_uint(sc) & KEYMASK) | kc;                 \
            const unsigned x_ = umx(m1v[s_], p); m1v[s_] = umn(m1v[s_], p);          \
            const unsigned y_ = umx(m2v[s_], x_); m2v[s_] = umn(m2v[s_], x_);        \
            m3v[s_] = umn(m3v[s_], y_);                                              \
        }                                                                            \
    }

    // Pipeline per tile i: write st(tile i+1) -> buf[(i+1)%3]  (st loaded 1 iter ago)
    //                      issue st <- tile i+2
    //                      compute buf[i%3]; ONE barrier.
    // Rewrite of buf[i%3] happens at iter i+2 top: two barriers after its last read.
    #define ITER3(bR, bW, tile_)                                                     \
        STAGE_WRITE(bW, st);                                                         \
        STAGE_LOAD(st, (tile_) + 2);                                                 \
        COMPUTE(bR, (tile_));                                                        \
        __syncthreads();

    for (int i = 0; i < 30; i += 3) {
        ITER3(buf0, buf1, i)
        ITER3(buf1, buf2, i + 1)
        ITER3(buf2, buf0, i + 2)
    }
    // tail: tile 30 (buf0 holds tile30, st holds tile31)
    STAGE_WRITE(buf1, st);
    COMPUTE(buf0, 30);
    __syncthreads();
    COMPUTE(buf1, 31);
    #undef ITER3
    #undef COMPUTE
    #undef STAGE_LOAD
    #undef STAGE_WRITE

    // ---- butterfly merge of top-3 across the 32 lanes of each half-wave ----
    #pragma unroll
    for (int s = 0; s < 16; ++s) {
        unsigned a1 = m1v[s], a2 = m2v[s], a3 = m3v[s];
        #pragma unroll
        for (int m = 1; m < 32; m <<= 1) {
            const unsigned b1 = (unsigned)__shfl_xor((int)a1, m, 64);
            const unsigned b2 = (unsigned)__shfl_xor((int)a2, m, 64);
            const unsigned b3 = (unsigned)__shfl_xor((int)a3, m, 64);
            const unsigned hi1 = umx(a1, b1), lo2 = umn(a2, b2);
            const unsigned r3  = umn(umx(hi1, lo2), umn(a3, b3));
            a1 = umn(a1, b1);
            a2 = umn(hi1, lo2);
            a3 = r3;
        }
        if (lr == s) {
            const int r = (s & 3) + ((s >> 2) << 3) + (half << 2);
            top1[wq0 + r] = a1; top2[wq0 + r] = a2; top3[wq0 + r] = a3;
        }
    }
    __syncthreads();

    // ---- per-query finalize: idx, ambiguity enqueue, loss ----
    if (t < QT2) {
        const unsigned k1 = top1[t], k2 = top2[t], k3 = top3[t];
        const int I1 = (int)(k1 & 1023u);
        fidx[t] = I1;
        out[ZQTOT + 1 + n0 + t] = (float)I1;
        const float v1 = __uint_as_float(k1 & KEYMASK);   // biased keys: positive floats
        const float v2 = __uint_as_float(k2 & KEYMASK);
        if (v2 - v1 < AMB_THR) {
            unsigned pos = atomicAdd(amb_cnt, 1u);
            if (pos < MAX_AMB)
                wl4[pos] = make_uint4((unsigned)(n0 + t),
                                      (k1 & 1023u) | ((k2 & 1023u) << 16),
                                      (k3 & 1023u) | ((k3 & 1023u) << 16), 0u);
        }
        float lq = zsql[t] + (v1 - BIAS);   // ||z-e||^2 = zsq + (esq - 2 dot)
        #pragma unroll
        for (int off = 32; off > 0; off >>= 1) lq += __shfl_down(lq, off, 64);
        if ((t & 63) == 0) lpart[t >> 6] = lq;
    }
    __syncthreads();
    if (t == 0)
        atomicAdd(loss_acc, (unsigned long long)(long long)((double)(lpart[0] + lpart[1]) * LOSS_SCALE));

    // ---- z_q write: stream emb[fidx] rows (STE output == e, tol 20.48) ----
    {
        const int q  = t & 127;
        const int dh = t >> 7;
        const int fq = fidx[q];
        const float4* ev = (const float4*)(emb + (size_t)fq * CDIM + dh * 128);
        float* ob = out + (size_t)b * BSTRIDE + (size_t)dh * 128 * SP + sp0 + q;
        #pragma unroll
        for (int i = 0; i < 32; ++i) {
            const float4 v = ev[i];
            float* o = ob + (size_t)(i * 4) * SP;
            o[0]            = v.x;
            o[SP]           = v.y;
            o[2*SP]         = v.z;
            o[(size_t)3*SP] = v.w;
        }
    }
}

// ---- fixup: wave-parallel np-exact, grid-stride; also emits the loss scalar ----
__global__ __launch_bounds__(64)
void vq_fix_cand(const float* __restrict__ z, const float* __restrict__ emb,
                 float* __restrict__ out, const unsigned int* __restrict__ amb_cnt,
                 const uint4* __restrict__ wl4,
                 const unsigned long long* __restrict__ loss_acc) {
    __shared__ float zrow[CDIM];
    __shared__ float erow[4][CDIM];
    __shared__ float dsh[4], esh[4];
    __shared__ float zss;

    // loss finalize (loss_acc complete: main kernel precedes in stream order)
    if (blockIdx.x == 0 && threadIdx.x == 0) {
        double mse = (double)(long long)(*loss_acc) / LOSS_SCALE / (double)ZQTOT;
        out[ZQTOT] = (float)(mse * 1.25);   // (1 + beta) * mse
    }

    unsigned cnt = *amb_cnt; if (cnt > MAX_AMB) cnt = MAX_AMB;
    const int l = threadIdx.x;

    for (unsigned widx = blockIdx.x; widx < cnt; widx += gridDim.x) {
        __syncthreads();    // protect LDS reuse across iterations
        const uint4 e = wl4[widx];
        const int n = (int)e.x;
        const int b = n >> 14, sp = n & 16383;
        int codes[4] = { (int)(e.y & 1023u), (int)((e.y >> 16) & 1023u),
                         (int)(e.z & 1023u), (int)((e.z >> 16) & 1023u) };

        #pragma unroll
        for (int i = 0; i < 4; ++i) {
            const int c = l + 64*i;
            zrow[c] = z[(size_t)b * BSTRIDE + (size_t)c * SP + sp];
        }
        {
            const int r = l >> 4, c0 = (l & 15) * 16;
            const float4* src = (const float4*)(emb + (size_t)codes[r] * CDIM + c0);
            float4* dst = (float4*)&erow[r][c0];
            #pragma unroll
            for (int i = 0; i < 4; ++i) dst[i] = src[i];
        }
        __syncthreads();

        const int role = l >> 4, rr = (l >> 2) & 3, a = l & 3;
        if (role == 0) {
            const float* er = erow[rr];
            float acc = __fmul_rn(zrow[a], er[a]);
            for (int i = 1; i < 64; ++i)
                acc = __fadd_rn(acc, __fmul_rn(zrow[4*i + a], er[4*i + a]));
            const float u = __fadd_rn(acc, __shfl_xor(acc, 1, 64));
            const float d = __fadd_rn(u,   __shfl_xor(u,   2, 64));  // (a0+a1)+(a2+a3)
            if (a == 0) dsh[rr] = d;
        } else if (role == 1 || (role == 2 && rr == 0)) {
            const float* src = (role == 1) ? erow[rr] : zrow;
            float pA = __fmul_rn(src[a],       src[a]);
            float pB = __fmul_rn(src[a+4],     src[a+4]);
            float qA = __fmul_rn(src[128+a],   src[128+a]);
            float qB = __fmul_rn(src[128+a+4], src[128+a+4]);
            #pragma unroll 4
            for (int i = 1; i < 16; ++i) {
                pA = __fadd_rn(pA, __fmul_rn(src[8*i+a],       src[8*i+a]));
                pB = __fadd_rn(pB, __fmul_rn(src[8*i+a+4],     src[8*i+a+4]));
                qA = __fadd_rn(qA, __fmul_rn(src[128+8*i+a],   src[128+8*i+a]));
                qB = __fadd_rn(qB, __fmul_rn(src[128+8*i+a+4], src[128+8*i+a+4]));
            }
            float uA = __fadd_rn(pA, __shfl_xor(pA, 1, 64));
            float vA = __fadd_rn(uA, __shfl_xor(uA, 2, 64));
            float uB = __fadd_rn(pB, __shfl_xor(pB, 1, 64));
            float vB = __fadd_rn(uB, __shfl_xor(uB, 2, 64));
            const float h0 = __fadd_rn(vA, vB);
            float uC = __fadd_rn(qA, __shfl_xor(qA, 1, 64));
            float vC = __fadd_rn(uC, __shfl_xor(uC, 2, 64));
            float uD = __fadd_rn(qB, __shfl_xor(qB, 1, 64));
            float vD = __fadd_rn(uD, __shfl_xor(uD, 2, 64));
            const float h1 = __fadd_rn(vC, vD);
            const float stot = __fadd_rn(h0, h1);
            if (a == 0) { if (role == 1) esh[rr] = stot; else zss = stot; }
        }
        __syncthreads();
        if (l == 0) {
            float bd = 3.4e38f; int bk = KCODES;
            #pragma unroll
            for (int i = 0; i < 4; ++i) {
                const float d = __fsub_rn(__fadd_rn(zss, esh[i]), __fmul_rn(2.0f, dsh[i]));
                if (d < bd || (d == bd && codes[i] < bk)) { bd = d; bk = codes[i]; }
            }
            out[ZQTOT + 1 + n] = (float)bk;   // np.argmin first-index semantics
        }
    }
}

// ---------------- fallback (round-3 proven path, used if ws too small) ----------------
__global__ __launch_bounds__(256)
void vq_main_basic(const float* __restrict__ z, const float* __restrict__ emb,
                   float* __restrict__ out, unsigned long long* __restrict__ loss_acc,
                   unsigned int* __restrict__ amb_cnt, unsigned int* __restrict__ wl) {
    __shared__ float zlz[64 * CDIM];
    __shared__ float esq[KCODES];
    __shared__ float m1s[4][64], m2s[4][64];
    __shared__ int   i1s[4][64];
    __shared__ int   fidx[64];
    __shared__ float lsum[4];

    const int t  = threadIdx.x;
    const int q  = t & 63;
    const int w  = __builtin_amdgcn_readfirstlane(t >> 6);
    const int qs = q & 7;
    const int n0 = blockIdx.x * 64;
    const int b  = n0 >> 14;
    const int sp0 = n0 & 16383;
    const float* zb = z + (size_t)b * BSTRIDE;

    #pragma unroll 4
    for (int i = 0; i < 64; ++i) {
        int c = (t >> 6) * 64 + i;
        float v = zb[(size_t)c * SP + sp0 + q];
        zlz[q * CDIM + ((((c >> 2) ^ qs) << 2) | (c & 3))] = v;
    }
    for (int k = t; k < KCODES; k += 256) {
        const float4* er = (const float4*)(emb + (size_t)k * CDIM);
        float s = 0.f;
        for (int c4 = 0; c4 < 64; ++c4) {
            float4 e = er[c4];
            s += e.x*e.x + e.y*e.y + e.z*e.z + e.w*e.w;
        }
        esq[k] = s;
    }
    __syncthreads();

    float m1 = 3.4e38f, m2 = 3.4e38f; int i1 = 0;
    const float* zrow = zlz + q * CDIM;
    const int kbase = w * 256;
    for (int kk = 0; kk < 256; kk += 8) {
        const int k0 = kbase + kk;
        float acc[8] = {0,0,0,0,0,0,0,0};
        for (int c4 = 0; c4 < 64; ++c4) {
            float4 zv = *(const float4*)(zrow + ((c4 ^ qs) << 2));
            #pragma unroll
            for (int j = 0; j < 8; ++j) {
                float4 ev = *(const float4*)(emb + (size_t)(k0 + j) * CDIM + (c4 << 2));
                acc[j] += zv.x*ev.x + zv.y*ev.y + zv.z*ev.z + zv.w*ev.w;
            }
        }
        #pragma unroll
        for (int j = 0; j < 8; ++j) {
            float s = esq[k0 + j] - 2.0f * acc[j];
            if (s < m1)      { m2 = m1; m1 = s; i1 = k0 + j; }
            else if (s < m2) { m2 = s; }
        }
    }
    m1s[w][q] = m1; m2s[w][q] = m2; i1s[w][q] = i1;
    __syncthreads();

    if (t < 64) {
        float M1 = 3.4e38f, M2 = 3.4e38f; int I1 = 0;
        for (int g = 0; g < 4; ++g) {
            float v1 = m1s[g][t], v2 = m2s[g][t];
            int   a1 = i1s[g][t];
            if (v1 < M1) { M2 = M1; M1 = v1; I1 = a1; }
            else if (v1 < M2) { M2 = v1; }
            if (v2 < M2) { M2 = v2; }
        }
        if (M2 - M1 < 1.5e-4f) {
            unsigned pos = atomicAdd(amb_cnt, 1u);
            if (pos < MAX_AMB) wl[pos] = n0 + t;
        }
        fidx[t] = I1;
        out[ZQTOT + 1 + n0 + t] = (float)I1;
    }
    __syncthreads();

    const int fq = fidx[q];
    const float* eq = emb + (size_t)fq * CDIM;
    float ls = 0.f;
    #pragma unroll 4
    for (int i = 0; i < 64; ++i) {
        int c = (t >> 6) * 64 + i;
        float zv = zrow[((((c >> 2) ^ qs) << 2) | (c & 3))];
        float ev = eq[c];
        float d = ev - zv;
        ls += d * d;
        out[(size_t)b * BSTRIDE + (size_t)c * SP + sp0 + q] = zv + d;
    }
    #pragma unroll
    for (int off = 32; off > 0; off >>= 1) ls += __shfl_down(ls, off, 64);
    if (q == 0) lsum[w] = ls;
    __syncthreads();
    if (t == 0) {
        float tot = lsum[0] + lsum[1] + lsum[2] + lsum[3];
        atomicAdd(loss_acc, (unsigned long long)(long long)((double)tot * LOSS_SCALE));
    }
}

__global__ __launch_bounds__(256)
void vq_fix_np(const float* __restrict__ z, const float* __restrict__ emb,
               float* __restrict__ out, const unsigned int* __restrict__ amb_cnt,
               const unsigned int* __restrict__ wl) {
    __shared__ float zrow[CDIM];
    __shared__ float zsq_sh;
    __shared__ float rd[256];
    __shared__ int   rk[256];

    unsigned cnt = *amb_cnt; if (cnt > MAX_AMB) cnt = MAX_AMB;
    if (blockIdx.x >= cnt) return;
    const int n = (int)wl[blockIdx.x];
    const int b = n >> 14, sp = n & 16383;
    const int t = threadIdx.x;

    zrow[t] = z[(size_t)b * BSTRIDE + (size_t)t * SP + sp];
    __syncthreads();
    if (t == 0) zsq_sh = pairwise256_sq(zrow);
    __syncthreads();
    const float zsq = zsq_sh;

    float bestd = 3.4e38f; int bestk = KCODES;
    for (int j = 0; j < 4; ++j) {
        const int k = t + 256 * j;
        const float* er = emb + (size_t)k * CDIM;
        const float dot = np_dot256(zrow, er);
        const float es  = pairwise256_sq(er);
        const float d   = __fsub_rn(__fadd_rn(zsq, es), __fmul_rn(2.0f, dot));
        if (d < bestd || (d == bestd && k < bestk)) { bestd = d; bestk = k; }
    }
    rd[t] = bestd; rk[t] = bestk;
    __syncthreads();
    for (int s = 128; s > 0; s >>= 1) {
        if (t < s) {
            float od = rd[t + s]; int ok = rk[t + s];
            if (od < rd[t] || (od == rd[t] && ok < rk[t])) { rd[t] = od; rk[t] = ok; }
        }
        __syncthreads();
    }
    if (t == 0) out[ZQTOT + 1 + n] = (float)rk[0];
}

__global__ void vq_final(const unsigned long long* __restrict__ acc, float* __restrict__ out) {
    if (threadIdx.x == 0 && blockIdx.x == 0) {
        double mse = (double)(long long)acc[0] / LOSS_SCALE / (double)ZQTOT;
        out[ZQTOT] = (float)(mse * 1.25);   // (1 + beta) * mse
    }
}

extern "C" void kernel_launch(void* const* d_in, const int* in_sizes, int n_in,
                              void* d_out, int out_size, void* d_ws, size_t ws_size,
                              hipStream_t stream) {
    const float* z   = (const float*)d_in[0];
    const float* emb = (const float*)d_in[1];
    float* out = (float*)d_out;

    unsigned long long* loss_acc = (unsigned long long*)d_ws;
    unsigned int* amb_cnt = (unsigned int*)((char*)d_ws + 8);
    const size_t WL4_OFF  = 64;
    const size_t ESQ_OFF  = (WL4_OFF + (size_t)MAX_AMB * 16 + 255) & ~(size_t)255;
    const size_t EMBH_OFF = (ESQ_OFF + (size_t)KCODES * 4 + 255) & ~(size_t)255;
    const size_t WS_NEED  = EMBH_OFF + (size_t)KCODES * CDIM * 2;

    hipMemsetAsync(d_ws, 0, 16, stream);
    if (ws_size >= WS_NEED) {
        uint4* wl4 = (uint4*)((char*)d_ws + WL4_OFF);
        float* esq_g = (float*)((char*)d_ws + ESQ_OFF);
        unsigned short* embh = (unsigned short*)((char*)d_ws + EMBH_OFF);
        vq_prep<<<dim3(KCODES), dim3(64), 0, stream>>>(emb, embh, esq_g);
        vq_main_mfma<<<dim3(NQ / QT2), dim3(256), 0, stream>>>(z, emb, embh, esq_g,
                                                               out, loss_acc, amb_cnt, wl4);
        vq_fix_cand<<<dim3(2048), dim3(64), 0, stream>>>(z, emb, out, amb_cnt, wl4, loss_acc);
    } else {
        unsigned int* wl = (unsigned int*)((char*)d_ws + WL4_OFF);
        vq_main_basic<<<dim3(NQ / 64), dim3(256), 0, stream>>>(z, emb, out, loss_acc, amb_cnt, wl);
        vq_fix_np<<<dim3(MAX_AMB), dim3(256), 0, stream>>>(z, emb, out, amb_cnt, wl);
        vq_final<<<dim3(1), dim3(64), 0, stream>>>(loss_acc, out);
    }
}

// Round 15
// 112.478 us; speedup vs baseline: 1.8962x; 1.8962x over previous
//
#include <hip/hip_runtime.h>

#define KCODES 1024
#define CDIM   256
#define SP     16384           // D*H*W
#define ZQTOT  16777216        // B*C*D*H*W
#define NQ     65536           // B*D*H*W
#define BSTRIDE 4194304        // C*SP
#define MAX_AMB 12288
#define LOSS_SCALE 33554432.0  // 2^25 fixed-point deterministic loss
#define KEYMASK 0xFFFFFC00u
#define AMB_THR 6.0e-4f
#define BIAS    0.25f

#define QT2    128             // queries per block (main kernel)
#define NTILE  32              // 32 code-tiles of 32 codes
#define ROWB   528             // padded LDS bytes per code row (33*16)
#define TILEB  16896           // 32*528

using f32x4  = __attribute__((ext_vector_type(4)))  float;
using f32x16 = __attribute__((ext_vector_type(16))) float;
using bf16x8 = __attribute__((ext_vector_type(8)))  short;

__device__ __forceinline__ unsigned short f2bf(float x) {   // RNE f32->bf16
    unsigned u = __float_as_uint(x);
    u += 0x7fffu + ((u >> 16) & 1u);
    return (unsigned short)(u >> 16);
}
__device__ __forceinline__ unsigned umn(unsigned a, unsigned b){ return a < b ? a : b; }
__device__ __forceinline__ unsigned umx(unsigned a, unsigned b){ return a > b ? a : b; }

// ---- numpy pairwise_sum replication (base case n=128, 8 accumulators) ----
__device__ __forceinline__ float pw128_sq(const float* a) {
    float r[8];
    #pragma unroll
    for (int j = 0; j < 8; ++j) r[j] = __fmul_rn(a[j], a[j]);
    for (int i = 8; i < 128; i += 8) {
        #pragma unroll
        for (int j = 0; j < 8; ++j) r[j] = __fadd_rn(r[j], __fmul_rn(a[i+j], a[i+j]));
    }
    return __fadd_rn(__fadd_rn(__fadd_rn(r[0], r[1]), __fadd_rn(r[2], r[3])),
                     __fadd_rn(__fadd_rn(r[4], r[5]), __fadd_rn(r[6], r[7])));
}
__device__ __forceinline__ float pairwise256_sq(const float* a) {
    return __fadd_rn(pw128_sq(a), pw128_sq(a + 128));
}
// np.einsum SSE path: 4 mod-4 accumulators, separate mul/add roundings
__device__ __forceinline__ float np_dot256(const float* zr, const float* er) {
    float a0 = 0.f, a1 = 0.f, a2 = 0.f, a3 = 0.f;
    for (int i8 = 0; i8 < 256; i8 += 8) {
        a0 = __fadd_rn(a0, __fmul_rn(zr[i8+0], er[i8+0]));
        a1 = __fadd_rn(a1, __fmul_rn(zr[i8+1], er[i8+1]));
        a2 = __fadd_rn(a2, __fmul_rn(zr[i8+2], er[i8+2]));
        a3 = __fadd_rn(a3, __fmul_rn(zr[i8+3], er[i8+3]));
        a0 = __fadd_rn(a0, __fmul_rn(zr[i8+4], er[i8+4]));
        a1 = __fadd_rn(a1, __fmul_rn(zr[i8+5], er[i8+5]));
        a2 = __fadd_rn(a2, __fmul_rn(zr[i8+6], er[i8+6]));
        a3 = __fadd_rn(a3, __fmul_rn(zr[i8+7], er[i8+7]));
    }
    return __fadd_rn(__fadd_rn(a0, a1), __fadd_rn(a2, a3));
}

// ---------------- pre-pass: emb -> bf16 (hi only) + BIASED esq ----------------
__global__ __launch_bounds__(64)
void vq_prep(const float* __restrict__ emb, unsigned short* __restrict__ embh,
             float* __restrict__ esq_g) {
    const int k = blockIdx.x;
    const int l = threadIdx.x;
    float4 v = ((const float4*)(emb + (size_t)k * CDIM))[l];
    float s = v.x*v.x + v.y*v.y + v.z*v.z + v.w*v.w;
    unsigned short h0=f2bf(v.x), h1=f2bf(v.y), h2=f2bf(v.z), h3=f2bf(v.w);
    uint2 hh; hh.x = (unsigned)h0 | ((unsigned)h1<<16); hh.y = (unsigned)h2 | ((unsigned)h3<<16);
    *(uint2*)&embh[(size_t)k*CDIM + l*4] = hh;
    #pragma unroll
    for (int off = 32; off > 0; off >>= 1) s += __shfl_down(s, off, 64);
    if (l == 0) esq_g[k] = s + BIAS;   // biased: all scores positive -> raw-bit keys
}

// ------- MFMA main: r13 exact (single prefetch, 1 barrier/tile, bias keys, setprio) -------
__global__ __launch_bounds__(256, 2)
void vq_main_mfma(const float* __restrict__ z, const float* __restrict__ emb,
                  const unsigned short* __restrict__ embh,
                  const float* __restrict__ esq_g,
                  float* __restrict__ out, unsigned long long* __restrict__ loss_acc,
                  unsigned int* __restrict__ amb_cnt, uint4* __restrict__ wl4) {
    __shared__ __align__(16) unsigned char smem[2*TILEB + 4096];
    unsigned* top1 = (unsigned*)(smem + 2*TILEB);          // 128 u32
    unsigned* top2 = top1 + 128;
    unsigned* top3 = top2 + 128;
    float*    zsql = (float*)(top3 + 128);                 // 128 f32
    int*      fidx = (int*)(zsql + 128);                   // 128 i32
    float*    lpart = (float*)(fidx + 128);                // 2 f32

    const int t    = threadIdx.x;
    const int l    = t & 63;
    const int w    = t >> 6;
    const int half = l >> 5;
    const int lr   = l & 31;
    // XCD-bijective swizzle (nwg=512, 512%8==0)
    const int bid  = blockIdx.x;
    const int obid = ((bid & 7) << 6) + (bid >> 3);
    const int n0   = obid * QT2;
    const int b    = n0 >> 14;
    const int sp0  = n0 & 16383;
    const int wq0  = w * 32;
    const float* zb = z + (size_t)b * BSTRIDE + sp0 + wq0 + lr;
    const char* ebase = (const char*)embh;

    // ---- issue tile-0 B stage loads (latency covered by A-load below) ----
    uint4 st[4];
    #pragma unroll
    for (int k = 0; k < 4; ++k)
        st[k] = *(const uint4*)(ebase + (size_t)(t + k*256) * 16);

    // ---- A fragments in registers: lane = query (lr), k-half (half) ----
    bf16x8 A[16];
    float zsq_p = 0.f;
    #pragma unroll
    for (int ks = 0; ks < 16; ++ks) {
        const float* zp = zb + (size_t)(ks*16 + half*8) * SP;
        float v[8];
        #pragma unroll
        for (int j = 0; j < 8; ++j) v[j] = zp[(size_t)j * SP];
        bf16x8 a;
        #pragma unroll
        for (int j = 0; j < 8; ++j) {
            zsq_p += v[j] * v[j];
            a[j] = (short)f2bf(v[j]);
        }
        A[ks] = a;
    }
    zsq_p += __shfl_xor(zsq_p, 32, 64);
    if (half == 0) zsql[wq0 + lr] = zsq_p;

    // ---- write tile 0 into LDS buffer 0 (padded rows) ----
    #pragma unroll
    for (int k = 0; k < 4; ++k) {
        const int idx = t + k*256;
        *(uint4*)(smem + (idx >> 5)*ROWB + (idx & 31)*16) = st[k];
    }
    __syncthreads();

    unsigned m1v[16], m2v[16], m3v[16];
    #pragma unroll
    for (int s = 0; s < 16; ++s) { m1v[s]=0xFFFFFFFFu; m2v[s]=0xFFFFFFFFu; m3v[s]=0xFFFFFFFFu; }

    int cur = 0;
    for (int tile = 0; tile < NTILE; ++tile) {
        // prefetch next tile's B into registers (issue early: MFMA phase covers)
        if (tile + 1 < NTILE) {
            #pragma unroll
            for (int k = 0; k < 4; ++k)
                st[k] = *(const uint4*)(ebase + (size_t)(tile+1)*16384 + (size_t)(t + k*256)*16);
        }
        const float es = esq_g[tile*32 + lr];

        // ---- 4 independent MFMA chains (ks mod 4); setprio biases pipe arbitration ----
        const unsigned char* bb = smem + cur*TILEB + lr*ROWB + half*16;
        f32x16 acc[4];
        #pragma unroll
        for (int c = 0; c < 4; ++c)
            acc[c] = f32x16{0.f,0.f,0.f,0.f,0.f,0.f,0.f,0.f,0.f,0.f,0.f,0.f,0.f,0.f,0.f,0.f};
        __builtin_amdgcn_s_setprio(1);
        #pragma unroll
        for (int ks = 0; ks < 16; ++ks) {
            const bf16x8 Bv = *(const bf16x8*)(bb + ks*32);
            acc[ks & 3] = __builtin_amdgcn_mfma_f32_32x32x16_bf16(A[ks], Bv, acc[ks & 3], 0, 0, 0);
        }
        __builtin_amdgcn_s_setprio(0);
        // fold: biased-positive scores -> raw float bits are monotone keys
        const unsigned kc = (unsigned)(tile*32 + lr);
        #pragma unroll
        for (int s = 0; s < 16; ++s) {
            const float dot = (acc[0][s] + acc[1][s]) + (acc[2][s] + acc[3][s]);
            const float sc = __builtin_fmaf(-2.0f, dot, es);
            const unsigned p = (__float_as_uint(sc) & KEYMASK) | kc;
            const unsigned x = umx(m1v[s], p); m1v[s] = umn(m1v[s], p);
            const unsigned y = umx(m2v[s], x); m2v[s] = umn(m2v[s], x);
            m3v[s] = umn(m3v[s], y);
        }
        // write next tile into the other buffer, then ONE barrier.
        if (tile + 1 < NTILE) {
            #pragma unroll
            for (int k = 0; k < 4; ++k) {
                const int idx = t + k*256;
                *(uint4*)(smem + (cur^1)*TILEB + (idx >> 5)*ROWB + (idx & 31)*16) = st[k];
            }
        }
        __syncthreads();
        cur ^= 1;
    }

    // ---- butterfly merge of top-3 across the 32 lanes of each half-wave ----
    #pragma unroll
    for (int s = 0; s < 16; ++s) {
        unsigned a1 = m1v[s], a2 = m2v[s], a3 = m3v[s];
        #pragma unroll
        for (int m = 1; m < 32; m <<= 1) {
            const unsigned b1 = (unsigned)__shfl_xor((int)a1, m, 64);
            const unsigned b2 = (unsigned)__shfl_xor((int)a2, m, 64);
            const unsigned b3 = (unsigned)__shfl_xor((int)a3, m, 64);
            const unsigned hi1 = umx(a1, b1), lo2 = umn(a2, b2);
            const unsigned r3  = umn(umx(hi1, lo2), umn(a3, b3));
            a1 = umn(a1, b1);
            a2 = umn(hi1, lo2);
            a3 = r3;
        }
        if (lr == s) {
            const int r = (s & 3) + ((s >> 2) << 3) + (half << 2);
            top1[wq0 + r] = a1; top2[wq0 + r] = a2; top3[wq0 + r] = a3;
        }
    }
    __syncthreads();

    // ---- per-query finalize: idx, ambiguity enqueue, loss ----
    if (t < QT2) {
        const unsigned k1 = top1[t], k2 = top2[t], k3 = top3[t];
        const int I1 = (int)(k1 & 1023u);
        fidx[t] = I1;
        out[ZQTOT + 1 + n0 + t] = (float)I1;
        const float v1 = __uint_as_float(k1 & KEYMASK);   // biased keys: positive floats
        const float v2 = __uint_as_float(k2 & KEYMASK);
        if (v2 - v1 < AMB_THR) {
            unsigned pos = atomicAdd(amb_cnt, 1u);
            if (pos < MAX_AMB)
                wl4[pos] = make_uint4((unsigned)(n0 + t),
                                      (k1 & 1023u) | ((k2 & 1023u) << 16),
                                      (k3 & 1023u) | ((k3 & 1023u) << 16), 0u);
        }
        float lq = zsql[t] + (v1 - BIAS);   // ||z-e||^2 = zsq + (esq - 2 dot)
        #pragma unroll
        for (int off = 32; off > 0; off >>= 1) lq += __shfl_down(lq, off, 64);
        if ((t & 63) == 0) lpart[t >> 6] = lq;
    }
    __syncthreads();
    if (t == 0)
        atomicAdd(loss_acc, (unsigned long long)(long long)((double)(lpart[0] + lpart[1]) * LOSS_SCALE));

    // ---- z_q write: stream emb[fidx] rows (STE output == e, tol 20.48) ----
    {
        const int q  = t & 127;
        const int dh = t >> 7;
        const int fq = fidx[q];
        const float4* ev = (const float4*)(emb + (size_t)fq * CDIM + dh * 128);
        float* ob = out + (size_t)b * BSTRIDE + (size_t)dh * 128 * SP + sp0 + q;
        #pragma unroll
        for (int i = 0; i < 32; ++i) {
            const float4 v = ev[i];
            float* o = ob + (size_t)(i * 4) * SP;
            o[0]            = v.x;
            o[SP]           = v.y;
            o[2*SP]         = v.z;
            o[(size_t)3*SP] = v.w;
        }
    }
}

// ---- fixup: np-exact, 4 queries/block (one per wave), uniform-iteration grid-stride ----
__global__ __launch_bounds__(256)
void vq_fix_cand(const float* __restrict__ z, const float* __restrict__ emb,
                 float* __restrict__ out, const unsigned int* __restrict__ amb_cnt,
                 const uint4* __restrict__ wl4,
                 const unsigned long long* __restrict__ loss_acc) {
    __shared__ float zrow[4][CDIM];
    __shared__ float erow[4][4][CDIM];
    __shared__ float dsh[4][4], esh[4][4];
    __shared__ float zss[4];

    // loss finalize (loss_acc complete: main kernel precedes in stream order)
    if (blockIdx.x == 0 && threadIdx.x == 0) {
        double mse = (double)(long long)(*loss_acc) / LOSS_SCALE / (double)ZQTOT;
        out[ZQTOT] = (float)(mse * 1.25);   // (1 + beta) * mse
    }

    unsigned cnt = *amb_cnt; if (cnt > MAX_AMB) cnt = MAX_AMB;
    const int t  = threadIdx.x;
    const int wv = t >> 6;           // wave id: each wave owns one worklist entry
    const int l  = t & 63;
    const unsigned stride = gridDim.x * 4;
    const unsigned nIter = (cnt + stride - 1) / stride;   // uniform across all waves

    for (unsigned j = 0; j < nIter; ++j) {
        __syncthreads();             // protect per-wave LDS slices across iterations
        const unsigned widx = (unsigned)blockIdx.x * 4 + wv + j * stride;
        const bool active = widx < cnt;
        int n = 0, b = 0, sp = 0;
        int codes[4] = {0, 0, 0, 0};
        if (active) {
            const uint4 e = wl4[widx];
            n = (int)e.x; b = n >> 14; sp = n & 16383;
            codes[0] = (int)(e.y & 1023u); codes[1] = (int)((e.y >> 16) & 1023u);
            codes[2] = (int)(e.z & 1023u); codes[3] = (int)((e.z >> 16) & 1023u);
            #pragma unroll
            for (int i = 0; i < 4; ++i) {
                const int c = l + 64*i;
                zrow[wv][c] = z[(size_t)b * BSTRIDE + (size_t)c * SP + sp];
            }
            const int r = l >> 4, c0 = (l & 15) * 16;
            const float4* src = (const float4*)(emb + (size_t)codes[r] * CDIM + c0);
            float4* dst = (float4*)&erow[wv][r][c0];
            #pragma unroll
            for (int i = 0; i < 4; ++i) dst[i] = src[i];
        }
        __syncthreads();
        if (active) {
            const int role = l >> 4, rr = (l >> 2) & 3, a = l & 3;
            if (role == 0) {
                // np.einsum dots: lane (rr,a) runs mod-4 accumulator 'a' for candidate rr
                const float* er = erow[wv][rr];
                const float* zr = zrow[wv];
                float acc = __fmul_rn(zr[a], er[a]);
                for (int i = 1; i < 64; ++i)
                    acc = __fadd_rn(acc, __fmul_rn(zr[4*i + a], er[4*i + a]));
                const float u = __fadd_rn(acc, __shfl_xor(acc, 1, 64));
                const float d = __fadd_rn(u,   __shfl_xor(u,   2, 64));  // (a0+a1)+(a2+a3)
                if (a == 0) dsh[wv][rr] = d;
            } else if (role == 1 || (role == 2 && rr == 0)) {
                // np pairwise_sum of squares: chains j=a, j=a+4, both 128-halves
                const float* src = (role == 1) ? erow[wv][rr] : zrow[wv];
                float pA = __fmul_rn(src[a],       src[a]);
                float pB = __fmul_rn(src[a+4],     src[a+4]);
                float qA = __fmul_rn(src[128+a],   src[128+a]);
                float qB = __fmul_rn(src[128+a+4], src[128+a+4]);
                #pragma unroll 4
                for (int i = 1; i < 16; ++i) {
                    pA = __fadd_rn(pA, __fmul_rn(src[8*i+a],       src[8*i+a]));
                    pB = __fadd_rn(pB, __fmul_rn(src[8*i+a+4],     src[8*i+a+4]));
                    qA = __fadd_rn(qA, __fmul_rn(src[128+8*i+a],   src[128+8*i+a]));
                    qB = __fadd_rn(qB, __fmul_rn(src[128+8*i+a+4], src[128+8*i+a+4]));
                }
                float uA = __fadd_rn(pA, __shfl_xor(pA, 1, 64));
                float vA = __fadd_rn(uA, __shfl_xor(uA, 2, 64));   // (r0+r1)+(r2+r3)
                float uB = __fadd_rn(pB, __shfl_xor(pB, 1, 64));
                float vB = __fadd_rn(uB, __shfl_xor(uB, 2, 64));   // (r4+r5)+(r6+r7)
                const float h0 = __fadd_rn(vA, vB);                // pw128 half0
                float uC = __fadd_rn(qA, __shfl_xor(qA, 1, 64));
                float vC = __fadd_rn(uC, __shfl_xor(uC, 2, 64));
                float uD = __fadd_rn(qB, __shfl_xor(qB, 1, 64));
                float vD = __fadd_rn(uD, __shfl_xor(uD, 2, 64));
                const float h1 = __fadd_rn(vC, vD);                // pw128 half1
                const float stot = __fadd_rn(h0, h1);
                if (a == 0) { if (role == 1) esh[wv][rr] = stot; else zss[wv] = stot; }
            }
        }
        __syncthreads();
        if (active && l == 0) {
            float bd = 3.4e38f; int bk = KCODES;
            #pragma unroll
            for (int i = 0; i < 4; ++i) {
                const float d = __fsub_rn(__fadd_rn(zss[wv], esh[wv][i]),
                                          __fmul_rn(2.0f, dsh[wv][i]));
                if (d < bd || (d == bd && codes[i] < bk)) { bd = d; bk = codes[i]; }
            }
            out[ZQTOT + 1 + n] = (float)bk;   // np.argmin first-index semantics
        }
    }
}

// ---------------- fallback (round-3 proven path, used if ws too small) ----------------
__global__ __launch_bounds__(256)
void vq_main_basic(const float* __restrict__ z, const float* __restrict__ emb,
                   float* __restrict__ out, unsigned long long* __restrict__ loss_acc,
                   unsigned int* __restrict__ amb_cnt, unsigned int* __restrict__ wl) {
    __shared__ float zlz[64 * CDIM];
    __shared__ float esq[KCODES];
    __shared__ float m1s[4][64], m2s[4][64];
    __shared__ int   i1s[4][64];
    __shared__ int   fidx[64];
    __shared__ float lsum[4];

    const int t  = threadIdx.x;
    const int q  = t & 63;
    const int w  = __builtin_amdgcn_readfirstlane(t >> 6);
    const int qs = q & 7;
    const int n0 = blockIdx.x * 64;
    const int b  = n0 >> 14;
    const int sp0 = n0 & 16383;
    const float* zb = z + (size_t)b * BSTRIDE;

    #pragma unroll 4
    for (int i = 0; i < 64; ++i) {
        int c = (t >> 6) * 64 + i;
        float v = zb[(size_t)c * SP + sp0 + q];
        zlz[q * CDIM + ((((c >> 2) ^ qs) << 2) | (c & 3))] = v;
    }
    for (int k = t; k < KCODES; k += 256) {
        const float4* er = (const float4*)(emb + (size_t)k * CDIM);
        float s = 0.f;
        for (int c4 = 0; c4 < 64; ++c4) {
            float4 e = er[c4];
            s += e.x*e.x + e.y*e.y + e.z*e.z + e.w*e.w;
        }
        esq[k] = s;
    }
    __syncthreads();

    float m1 = 3.4e38f, m2 = 3.4e38f; int i1 = 0;
    const float* zrow = zlz + q * CDIM;
    const int kbase = w * 256;
    for (int kk = 0; kk < 256; kk += 8) {
        const int k0 = kbase + kk;
        float acc[8] = {0,0,0,0,0,0,0,0};
        for (int c4 = 0; c4 < 64; ++c4) {
            float4 zv = *(const float4*)(zrow + ((c4 ^ qs) << 2));
            #pragma unroll
            for (int j = 0; j < 8; ++j) {
                float4 ev = *(const float4*)(emb + (size_t)(k0 + j) * CDIM + (c4 << 2));
                acc[j] += zv.x*ev.x + zv.y*ev.y + zv.z*ev.z + zv.w*ev.w;
            }
        }
        #pragma unroll
        for (int j = 0; j < 8; ++j) {
            float s = esq[k0 + j] - 2.0f * acc[j];
            if (s < m1)      { m2 = m1; m1 = s; i1 = k0 + j; }
            else if (s < m2) { m2 = s; }
        }
    }
    m1s[w][q] = m1; m2s[w][q] = m2; i1s[w][q] = i1;
    __syncthreads();

    if (t < 64) {
        float M1 = 3.4e38f, M2 = 3.4e38f; int I1 = 0;
        for (int g = 0; g < 4; ++g) {
            float v1 = m1s[g][t], v2 = m2s[g][t];
            int   a1 = i1s[g][t];
            if (v1 < M1) { M2 = M1; M1 = v1; I1 = a1; }
            else if (v1 < M2) { M2 = v1; }
            if (v2 < M2) { M2 = v2; }
        }
        if (M2 - M1 < 1.5e-4f) {
            unsigned pos = atomicAdd(amb_cnt, 1u);
            if (pos < MAX_AMB) wl[pos] = n0 + t;
        }
        fidx[t] = I1;
        out[ZQTOT + 1 + n0 + t] = (float)I1;
    }
    __syncthreads();

    const int fq = fidx[q];
    const float* eq = emb + (size_t)fq * CDIM;
    float ls = 0.f;
    #pragma unroll 4
    for (int i = 0; i < 64; ++i) {
        int c = (t >> 6) * 64 + i;
        float zv = zrow[((((c >> 2) ^ qs) << 2) | (c & 3))];
        float ev = eq[c];
        float d = ev - zv;
        ls += d * d;
        out[(size_t)b * BSTRIDE + (size_t)c * SP + sp0 + q] = zv + d;
    }
    #pragma unroll
    for (int off = 32; off > 0; off >>= 1) ls += __shfl_down(ls, off, 64);
    if (q == 0) lsum[w] = ls;
    __syncthreads();
    if (t == 0) {
        float tot = lsum[0] + lsum[1] + lsum[2] + lsum[3];
        atomicAdd(loss_acc, (unsigned long long)(long long)((double)tot * LOSS_SCALE));
    }
}

__global__ __launch_bounds__(256)
void vq_fix_np(const float* __restrict__ z, const float* __restrict__ emb,
               float* __restrict__ out, const unsigned int* __restrict__ amb_cnt,
               const unsigned int* __restrict__ wl) {
    __shared__ float zrow[CDIM];
    __shared__ float zsq_sh;
    __shared__ float rd[256];
    __shared__ int   rk[256];

    unsigned cnt = *amb_cnt; if (cnt > MAX_AMB) cnt = MAX_AMB;
    if (blockIdx.x >= cnt) return;
    const int n = (int)wl[blockIdx.x];
    const int b = n >> 14, sp = n & 16383;
    const int t = threadIdx.x;

    zrow[t] = z[(size_t)b * BSTRIDE + (size_t)t * SP + sp];
    __syncthreads();
    if (t == 0) zsq_sh = pairwise256_sq(zrow);
    __syncthreads();
    const float zsq = zsq_sh;

    float bestd = 3.4e38f; int bestk = KCODES;
    for (int j = 0; j < 4; ++j) {
        const int k = t + 256 * j;
        const float* er = emb + (size_t)k * CDIM;
        const float dot = np_dot256(zrow, er);
        const float es  = pairwise256_sq(er);
        const float d   = __fsub_rn(__fadd_rn(zsq, es), __fmul_rn(2.0f, dot));
        if (d < bestd || (d == bestd && k < bestk)) { bestd = d; bestk = k; }
    }
    rd[t] = bestd; rk[t] = bestk;
    __syncthreads();
    for (int s = 128; s > 0; s >>= 1) {
        if (t < s) {
            float od = rd[t + s]; int ok = rk[t + s];
            if (od < rd[t] || (od == rd[t] && ok < rk[t])) { rd[t] = od; rk[t] = ok; }
        }
        __syncthreads();
    }
    if (t == 0) out[ZQTOT + 1 + n] = (float)rk[0];
}

__global__ void vq_final(const unsigned long long* __restrict__ acc, float* __restrict__ out) {
    if (threadIdx.x == 0 && blockIdx.x == 0) {
        double mse = (double)(long long)acc[0] / LOSS_SCALE / (double)ZQTOT;
        out[ZQTOT] = (float)(mse * 1.25);   // (1 + beta) * mse
    }
}

extern "C" void kernel_launch(void* const* d_in, const int* in_sizes, int n_in,
                              void* d_out, int out_size, void* d_ws, size_t ws_size,
                              hipStream_t stream) {
    const float* z   = (const float*)d_in[0];
    const float* emb = (const float*)d_in[1];
    float* out = (float*)d_out;

    unsigned long long* loss_acc = (unsigned long long*)d_ws;
    unsigned int* amb_cnt = (unsigned int*)((char*)d_ws + 8);
    const size_t WL4_OFF  = 64;
    const size_t ESQ_OFF  = (WL4_OFF + (size_t)MAX_AMB * 16 + 255) & ~(size_t)255;
    const size_t EMBH_OFF = (ESQ_OFF + (size_t)KCODES * 4 + 255) & ~(size_t)255;
    const size_t WS_NEED  = EMBH_OFF + (size_t)KCODES * CDIM * 2;

    hipMemsetAsync(d_ws, 0, 16, stream);
    if (ws_size >= WS_NEED) {
        uint4* wl4 = (uint4*)((char*)d_ws + WL4_OFF);
        float* esq_g = (float*)((char*)d_ws + ESQ_OFF);
        unsigned short* embh = (unsigned short*)((char*)d_ws + EMBH_OFF);
        vq_prep<<<dim3(KCODES), dim3(64), 0, stream>>>(emb, embh, esq_g);
        vq_main_mfma<<<dim3(NQ / QT2), dim3(256), 0, stream>>>(z, emb, embh, esq_g,
                                                               out, loss_acc, amb_cnt, wl4);
        vq_fix_cand<<<dim3(1024), dim3(256), 0, stream>>>(z, emb, out, amb_cnt, wl4, loss_acc);
    } else {
        unsigned int* wl = (unsigned int*)((char*)d_ws + WL4_OFF);
        vq_main_basic<<<dim3(NQ / 64), dim3(256), 0, stream>>>(z, emb, out, loss_acc, amb_cnt, wl);
        vq_fix_np<<<dim3(MAX_AMB), dim3(256), 0, stream>>>(z, emb, out, amb_cnt, wl);
        vq_final<<<dim3(1), dim3(64), 0, stream>>>(loss_acc, out);
    }
}